// Round 4
// baseline (203.340 us; speedup 1.0000x reference)
//
#include <hip/hip_runtime.h>
#include <hip/hip_bf16.h>
#include <stdint.h>

// Problem constants (N,C,H,W = 4,128,64,64)
#define NB 4
#define CH 128
#define LL 4096   // H*W

typedef __attribute__((ext_vector_type(8))) short short8;   // 8 bf16 MFMA A/B frag
typedef __attribute__((ext_vector_type(4))) short short4b;  // 4 bf16 (8B)
typedef __attribute__((ext_vector_type(4))) float floatx4;  // 16x16 C/D frag
typedef __attribute__((ext_vector_type(16))) float floatx16; // 32x32 C/D frag

// Frag-major layout (verified R9-R13): element (row r, k) of 16-wide tile t:
//   t*2048 + (k>>5)*512 + ((k>>3)&3)*128 + (r&15)*8 + (k&7)
// One 16x16x32 frag (tile t, slice s) = 512 contiguous shorts; lane L reads
// [8L, 8L+8) — fully coalesced; identical mapping for A- and B-frags.
//
// R15: XCD pinning (kept: FETCH 39.7->14.9 MB proved the L2 mechanism).
// R17: back to R0 geometry (256 blk x 1024 thr, m=64, 16 steps) — R3 showed
// smaller blocks/more barriers regress. NEW: A(t+1) and B(t) share one
// barrier interval (P dbuf makes them independent): B's V-latency hides
// under A's MFMA/exp, A's VALU chain hides under B's MFMA chain. K/D
// prefetched two intervals ahead; V issued at interval top, consumed late.

static __device__ __forceinline__ short f2bf(float f) {
    uint32_t u = __float_as_uint(f);
    u += 0x7fffu + ((u >> 16) & 1u);
    return (short)(u >> 16);
}
static __device__ __forceinline__ float bf2f(short s) {
    return __uint_as_float(((uint32_t)(uint16_t)s) << 16);
}

// ---------------------------------------------------------------------------
// Kernel 0: W prep — Wq/Wk/Wv fp32 [o][c] -> bf16 frag-major A-layout
// (rows=o, k=c). K-scale folded into Wk. (unchanged)
// ---------------------------------------------------------------------------
__global__ __launch_bounds__(256) void wprep_kernel(
    const float* __restrict__ Wq, const float* __restrict__ Wk,
    const float* __restrict__ Wv, short* __restrict__ Wf)
{
    const int g = blockIdx.x * 256 + threadIdx.x;   // 0..49151
    const int mat = g >> 14;
    const int rem = g & 16383;
    const int o   = rem >> 7;
    const int c   = rem & 127;
    const float* W = (mat == 0) ? Wq : (mat == 1) ? Wk : Wv;
    float v = W[o * CH + c];
    if (mat == 1) v *= 0.08838834764831845f;
    Wf[(size_t)mat * 16384 + (o >> 4) * 2048 + (c >> 5) * 512
       + ((c >> 3) & 3) * 128 + (o & 15) * 8 + (c & 7)] = f2bf(v);
}

// ---------------------------------------------------------------------------
// Kernel 1: QKV projection via MFMA (R12-proven structure).
// Outputs Qf/Kf frag-major, Vp panel [n][l>>4][c][l&15].
// grid = 512 blocks x 256 thr. XCD-pinned block remap.
// ---------------------------------------------------------------------------
__global__ __launch_bounds__(256) void proj_kernel(
    const float* __restrict__ x, const short* __restrict__ Wf,
    const float* __restrict__ bq, const float* __restrict__ bk,
    const float* __restrict__ bv,
    short* __restrict__ Qf, short* __restrict__ Kf, short* __restrict__ Vp)
{
    const int i    = blockIdx.x;
    const int n    = (i >> 1) & 3;            // XCD pair {2n,2n+1}
    const int lt   = ((i >> 3) << 1) | (i & 1); // l-tile of 32 (0..127)
    const int l0   = lt << 5;
    const int tid  = threadIdx.x;
    const int wave = tid >> 6;        // 0..3
    const int lane = tid & 63;
    const int quad = lane >> 4;
    const int mc   = lane & 15;

    __shared__ short Xb[32][136];     // [l][c] bf16, +8 pad (8.7 KB)

    {
        const int sl = tid & 31;      // l
        const int cg = tid >> 5;      // c-group of 16 (0..7)
        const float* xp = x + ((size_t)n * CH + cg * 16) * LL + l0 + sl;
        short8 buf;
        #pragma unroll
        for (int i2 = 0; i2 < 16; ++i2) {
            buf[i2 & 7] = f2bf(xp[(size_t)i2 * LL]);
            if ((i2 & 7) == 7)
                *(short8*)(void*)&Xb[sl][cg * 16 + (i2 & 8)] = buf;
        }
    }
    __syncthreads();

    const int lt2 = wave >> 1;        // l-subtile of 16
    const int oh  = wave & 1;         // o-half (4 o-tiles)
    const int gt  = lt * 2 + lt2;     // global 16-l tile index

    short8 xf[4];                     // B-frags: B[k=c][col=l]
    #pragma unroll
    for (int s = 0; s < 4; ++s)
        xf[s] = *(const short8*)(const void*)&Xb[lt2 * 16 + mc][32 * s + quad * 8];

    const size_t obase = ((size_t)n * 256 + gt) * 2048;
    const float scale = 0.08838834764831845f;  // 1/sqrt(128)

    #pragma unroll
    for (int mat = 0; mat < 3; ++mat) {
        const short* Wm = Wf + (size_t)mat * 16384;
        const float* bb = (mat == 0) ? bq : (mat == 1) ? bk : bv;
        const float bscale = (mat == 1) ? scale : 1.0f;
        #pragma unroll
        for (int ot = oh * 4; ot < oh * 4 + 4; ++ot) {
            floatx4 acc = {0.f, 0.f, 0.f, 0.f};
            #pragma unroll
            for (int s = 0; s < 4; ++s)
                acc = __builtin_amdgcn_mfma_f32_16x16x32_bf16(
                    *(const short8*)(const void*)(Wm + ot * 2048 + s * 512 + lane * 8),
                    xf[s], acc, 0, 0, 0);
            const int c0 = ot * 16 + 4 * quad;
            if (mat < 2) {
                short4b pv;
                #pragma unroll
                for (int r = 0; r < 4; ++r)
                    pv[r] = f2bf(acc[r] + bb[c0 + r] * bscale);
                short* dst = ((mat == 0) ? Qf : Kf) + obase
                           + (c0 >> 5) * 512 + ((c0 >> 3) & 3) * 128
                           + mc * 8 + (c0 & 7);
                *(short4b*)(void*)dst = pv;
            } else {
                #pragma unroll
                for (int r = 0; r < 4; ++r)
                    Vp[obase + (c0 + r) * 16 + mc] = f2bf(acc[r] + bb[c0 + r]);
            }
        }
    }
}

// ---------------------------------------------------------------------------
// Kernel 2: softmax denominators -> rcpD[n][l] floats. (R14 structure)
// 256 blocks x 1024 thr; 4 K-tiles/block; ping-pong Q prefetch.
// XCD-pinned block remap (Qf re-reads become XCD-L2 hits).
// ---------------------------------------------------------------------------
__global__ __launch_bounds__(1024) void rowsum_kernel(
    const short* __restrict__ Qf, const short* __restrict__ Kf,
    float* __restrict__ Dv)
{
    const int i    = blockIdx.x;         // 256 blocks
    const int n    = (i >> 1) & 3;       // XCD pair {2n,2n+1}
    const int tq   = ((i >> 3) << 1) | (i & 1);  // 64-l group (0..63)
    const int tid  = threadIdx.x;
    const int wave = tid >> 6;           // 0..15
    const int lane = tid & 63;
    const int quad = lane >> 4;
    const int mc   = lane & 15;
    const int mw   = wave & 7;           // m-eighth (512 m = 32 q-tiles)
    const int th   = wave >> 3;          // K-tile half (2 of the 4 tiles)

    __shared__ float Db[16][32];         // per-wave partial D (2 KB)

    const short* Kb = Kf + ((size_t)n * 256 + tq * 4 + th * 2) * 2048 + lane * 8;
    short8 kf[2][4];
    #pragma unroll
    for (int t = 0; t < 2; ++t)
        #pragma unroll
        for (int s = 0; s < 4; ++s)
            kf[t][s] = *(const short8*)(const void*)(Kb + t * 2048 + s * 512);

    const short* Qn = Qf + (size_t)n * 524288 + (size_t)mw * 32 * 2048 + lane * 8;
    float rs[2][4] = {{0.f, 0.f, 0.f, 0.f}, {0.f, 0.f, 0.f, 0.f}};

    short8 qA[4], qB[4];
    #pragma unroll
    for (int s = 0; s < 4; ++s)
        qA[s] = *(const short8*)(const void*)(Qn + s * 512);

    auto qstep = [&](const short8 (&q)[4]) {
        floatx4 a0 = {0.f, 0.f, 0.f, 0.f};
        floatx4 a1 = {0.f, 0.f, 0.f, 0.f};
        #pragma unroll
        for (int s = 0; s < 4; ++s) {
            a0 = __builtin_amdgcn_mfma_f32_16x16x32_bf16(kf[0][s], q[s], a0, 0, 0, 0);
            a1 = __builtin_amdgcn_mfma_f32_16x16x32_bf16(kf[1][s], q[s], a1, 0, 0, 0);
        }
        #pragma unroll
        for (int r = 0; r < 4; ++r) {
            rs[0][r] += __expf(a0[r]);
            rs[1][r] += __expf(a1[r]);
        }
    };

    for (int it = 0; it < 32; it += 2) {
        // prefetch tile it+1 while computing tile it
        #pragma unroll
        for (int s = 0; s < 4; ++s)
            qB[s] = *(const short8*)(const void*)(
                Qn + (size_t)((it + 1) & 31) * 2048 + s * 512);
        qstep(qA);
        // prefetch tile it+2 while computing tile it+1 (wrap at end: harmless)
        #pragma unroll
        for (int s = 0; s < 4; ++s)
            qA[s] = *(const short8*)(const void*)(
                Qn + (size_t)((it + 2) & 31) * 2048 + s * 512);
        qstep(qB);
    }

    // reduce over m within wave (cols live in mc lanes), then across 8 m-waves
    #pragma unroll
    for (int t = 0; t < 2; ++t)
        #pragma unroll
        for (int r = 0; r < 4; ++r) {
            float v = rs[t][r];
            v += __shfl_xor(v, 1);
            v += __shfl_xor(v, 2);
            v += __shfl_xor(v, 4);
            v += __shfl_xor(v, 8);
            if (mc == 0) Db[wave][t * 16 + quad * 4 + r] = v;  // local l = th*32+t*16+quad*4+r
        }
    __syncthreads();
    if (tid < 64) {
        const int lh = tid >> 5, lr = tid & 31;
        float s = 0.f;
        #pragma unroll
        for (int m = 0; m < 8; ++m) s += Db[lh * 8 + m][lr];
        Dv[(size_t)n * 4096 + tq * 64 + tid] = 1.0f / s;
    }
}

// ---------------------------------------------------------------------------
// Kernel 3 (R17): O[c,m] = sum_l V[c,l]*exp(S[l,m])/D[l];  out = x + O.
// R0 geometry: 256 blk x 1024 thr, m-block 64, 16 steps, P dbuf, 1 barrier
// per interval. NEW: interval t = { V(t) loads; K(t+2)/D(t+2) prefetch;
// A(t+1) -> P[p^1]; B(t) from P[p]; barrier }. A(t+1) and B(t) independent
// (dbuf) -> latencies mutually hidden. A(0) in prologue.
// ---------------------------------------------------------------------------
__global__ __launch_bounds__(1024) void attn_out_kernel(
    const short* __restrict__ Qf, const short* __restrict__ Kf,
    const short* __restrict__ Vp, const float* __restrict__ Dv,
    const float* __restrict__ x, float* __restrict__ out)
{
    const int i    = blockIdx.x;
    const int n    = (i >> 1) & 3;               // XCD pair {2n,2n+1}
    const int mb   = ((i >> 3) << 1) | (i & 1);  // m-block (0..63)
    const int m0   = mb << 6;            // m-block of 64
    const int tid  = threadIdx.x;
    const int wave = tid >> 6;          // 0..15
    const int lane = tid & 63;
    const int quad = lane >> 4;
    const int mc   = lane & 15;
    const int l32  = lane & 31;
    const int h    = lane >> 5;
    const int ct   = wave & 3;          // c-tile (32 channels)
    const int mh   = (wave >> 2) & 1;   // m-half (32 cols)
    const int kh   = wave >> 3;         // kc-half

    __shared__ short P[2][64][264];     // dbuf [m][l-local 256 +8] (67.6 KB)
    __shared__ float Rbuf[4][2][64][16]; // kh-pair reduce (32 KB)

    const short* Qn  = Qf + (size_t)n * 524288;
    const short* Kn  = Kf + (size_t)n * 524288;
    const short* Vpn = Vp + (size_t)n * 524288;
    const float* Dn  = Dv + (size_t)n * 4096;

    // resident Q B-frags (4 m-tiles x 4 slices)
    short8 qf[4][4];
    #pragma unroll
    for (int mst = 0; mst < 4; ++mst)
        #pragma unroll
        for (int s = 0; s < 4; ++s)
            qf[mst][s] = *(const short8*)(const void*)(
                Qn + (size_t)((m0 >> 4) + mst) * 2048 + s * 512 + lane * 8);

    floatx16 acc;
    #pragma unroll
    for (int r = 0; r < 16; ++r) acc[r] = 0.f;

    // ---- prologue: K(0)/D(0), A(0) -> P[0]; prefetch K(1)/D(1) ----
    short8 knxt[4];
    #pragma unroll
    for (int s = 0; s < 4; ++s)
        knxt[s] = *(const short8*)(const void*)(
            Kn + (size_t)wave * 2048 + s * 512 + lane * 8);
    floatx4 dnxt = *(const floatx4*)(const void*)(Dn + wave * 16 + quad * 4);

    #pragma unroll
    for (int mst = 0; mst < 4; ++mst) {
        floatx4 sa = {0.f, 0.f, 0.f, 0.f};
        #pragma unroll
        for (int s = 0; s < 4; ++s)
            sa = __builtin_amdgcn_mfma_f32_16x16x32_bf16(knxt[s], qf[mst][s], sa, 0, 0, 0);
        short4b pv;
        #pragma unroll
        for (int r = 0; r < 4; ++r) pv[r] = f2bf(__expf(sa[r]) * dnxt[r]);
        *(short4b*)(void*)&P[0][16 * mst + mc][16 * wave + quad * 4] = pv;
    }
    #pragma unroll
    for (int s = 0; s < 4; ++s)
        knxt[s] = *(const short8*)(const void*)(
            Kn + (size_t)(16 + wave) * 2048 + s * 512 + lane * 8);
    dnxt = *(const floatx4*)(const void*)(Dn + 256 + wave * 16 + quad * 4);
    __syncthreads();

    // ---- main loop: interval t = {V(t); K(t+2); A(t+1); B(t); bar} ----
    #pragma unroll 2
    for (int t = 0; t < 16; ++t) {
        const int lb = t << 8;          // 256 l this step
        const int p  = t & 1;

        // V(t) first half — consumed at interval end (max distance)
        short8 vf0[4];
        #pragma unroll
        for (int s = 0; s < 4; ++s)
            vf0[s] = *(const short8*)(const void*)(
                Vpn + (size_t)((lb >> 4) + kh * 8 + s) * 2048
                    + (32 * ct + l32) * 16 + 8 * h);

        // prefetch K(t+2)/D(t+2) (clamped; consumed next interval's A)
        const int tf = (t + 2 < 16) ? t + 2 : 15;
        short8 kfut[4];
        #pragma unroll
        for (int s = 0; s < 4; ++s)
            kfut[s] = *(const short8*)(const void*)(
                Kn + (size_t)(tf * 16 + wave) * 2048 + s * 512 + lane * 8);
        const floatx4 dfut = *(const floatx4*)(const void*)(
            Dn + (tf << 8) + wave * 16 + quad * 4);

        // ---- A(t+1): S rows [(t+1)*256+16w .. +16) x 64 m -> P[p^1] ----
        if (t < 15) {
            #pragma unroll
            for (int mst = 0; mst < 4; ++mst) {
                floatx4 sa = {0.f, 0.f, 0.f, 0.f};
                #pragma unroll
                for (int s = 0; s < 4; ++s)
                    sa = __builtin_amdgcn_mfma_f32_16x16x32_bf16(knxt[s], qf[mst][s], sa, 0, 0, 0);
                short4b pv;
                #pragma unroll
                for (int r = 0; r < 4; ++r) pv[r] = f2bf(__expf(sa[r]) * dnxt[r]);
                *(short4b*)(void*)&P[p ^ 1][16 * mst + mc][16 * wave + quad * 4] = pv;
            }
        }

        // V(t) second half
        short8 vf1[4];
        #pragma unroll
        for (int s = 0; s < 4; ++s)
            vf1[s] = *(const short8*)(const void*)(
                Vpn + (size_t)((lb >> 4) + kh * 8 + 4 + s) * 2048
                    + (32 * ct + l32) * 16 + 8 * h);

        // ---- B(t): V panel x P[p]; wave covers kc-half (8 chunks) ----
        #pragma unroll
        for (int i2 = 0; i2 < 4; ++i2) {
            const int kc = kh * 8 + i2;
            const short8 pf = *(const short8*)(const void*)&P[p][32 * mh + l32][16 * kc + 8 * h];
            acc = __builtin_amdgcn_mfma_f32_32x32x16_bf16(vf0[i2], pf, acc, 0, 0, 0);
        }
        #pragma unroll
        for (int i2 = 0; i2 < 4; ++i2) {
            const int kc = kh * 8 + 4 + i2;
            const short8 pf = *(const short8*)(const void*)&P[p][32 * mh + l32][16 * kc + 8 * h];
            acc = __builtin_amdgcn_mfma_f32_32x32x16_bf16(vf1[i2], pf, acc, 0, 0, 0);
        }

        __syncthreads();   // P[p^1] complete for B(t+1); P[p] free for A(t+2)

        #pragma unroll
        for (int s = 0; s < 4; ++s) knxt[s] = kfut[s];
        dnxt = dfut;
    }

    // ---- kh-pair reduce + epilogue (32x32 C-layout) ----
    if (kh == 1)
        *(floatx16*)(void*)&Rbuf[ct][mh][lane][0] = acc;
    __syncthreads();
    if (kh == 0) {
        const floatx16 o = *(const floatx16*)(const void*)&Rbuf[ct][mh][lane][0];
        #pragma unroll
        for (int r = 0; r < 16; ++r) {
            const int c = 32 * ct + (r & 3) + 8 * (r >> 2) + 4 * h;
            const int m = m0 + 32 * mh + l32;
            const size_t idx = ((size_t)n * CH + c) * LL + m;
            out[idx] = x[idx] + acc[r] + o[r];
        }
    }
}

// ---------------------------------------------------------------------------
extern "C" void kernel_launch(void* const* d_in, const int* in_sizes, int n_in,
                              void* d_out, int out_size, void* d_ws, size_t ws_size,
                              hipStream_t stream) {
    (void)in_sizes; (void)n_in; (void)out_size; (void)ws_size;
    const float* x  = (const float*)d_in[0];
    const float* Wq = (const float*)d_in[1];
    const float* bq = (const float*)d_in[2];
    const float* Wk = (const float*)d_in[3];
    const float* bk = (const float*)d_in[4];
    const float* Wv = (const float*)d_in[5];
    const float* bv = (const float*)d_in[6];
    float* out = (float*)d_out;

    char* ws = (char*)d_ws;
    // ws: Qf 4MB | Kf 4MB | Vp 4MB | Dv 64KB | Wf 96KB
    short* Qf = (short*)(ws);
    short* Kf = (short*)(ws + 4194304);
    short* Vp = (short*)(ws + 8388608);
    float* Dv = (float*)(ws + 12582912);
    short* Wf = (short*)(ws + 16777216);

    wprep_kernel<<<192, 256, 0, stream>>>(Wq, Wk, Wv, Wf);
    proj_kernel<<<512, 256, 0, stream>>>(x, Wf, bq, bk, bv, Qf, Kf, Vp);
    rowsum_kernel<<<256, 1024, 0, stream>>>(Qf, Kf, Dv);
    attn_out_kernel<<<256, 1024, 0, stream>>>(Qf, Kf, Vp, Dv, x, out);
}

// Round 5
// 157.841 us; speedup vs baseline: 1.2883x; 1.2883x over previous
//
#include <hip/hip_runtime.h>
#include <hip/hip_bf16.h>
#include <stdint.h>

// Problem constants (N,C,H,W = 4,128,64,64)
#define NB 4
#define CH 128
#define LL 4096   // H*W

typedef __attribute__((ext_vector_type(8))) short short8;   // 8 bf16 MFMA A/B frag
typedef __attribute__((ext_vector_type(4))) short short4b;  // 4 bf16 (8B)
typedef __attribute__((ext_vector_type(4))) float floatx4;  // 16x16 C/D frag
typedef __attribute__((ext_vector_type(16))) float floatx16; // 32x32 C/D frag

// Frag-major layout (verified R9-R13): element (row r, k) of 16-wide tile t:
//   t*2048 + (k>>5)*512 + ((k>>3)&3)*128 + (r&15)*8 + (k&7)
//
// R15: XCD pinning (FETCH 39.7->14.9 MB, kept).
// R18 (this round): attn_out l-split for CU co-residency.
//   R2 evidence: not BW-bound (2.7x traffic drop, no time change).
//   R3 evidence: smaller barrier intervals hurt. R4 evidence: in-block reg
//   pipelining spills (FETCH 114 MB). Remaining lever: 2 blocks/CU so one
//   block's compute fills the other's barrier/latency stalls.
//   grid 512 = {n, m64, l-half}; 512 thr; 8 steps/block; LDS 66 KB (no
//   Rbuf); partial O (f32) to ws; combine kernel adds halves + x.
//   rowsum likewise 512x512thr for 2 blocks/CU (identical per-wave work).

static __device__ __forceinline__ short f2bf(float f) {
    uint32_t u = __float_as_uint(f);
    u += 0x7fffu + ((u >> 16) & 1u);
    return (short)(u >> 16);
}
static __device__ __forceinline__ float bf2f(short s) {
    return __uint_as_float(((uint32_t)(uint16_t)s) << 16);
}

// ---------------------------------------------------------------------------
// Kernel 0: W prep — Wq/Wk/Wv fp32 [o][c] -> bf16 frag-major A-layout
// (rows=o, k=c). K-scale folded into Wk. (unchanged)
// ---------------------------------------------------------------------------
__global__ __launch_bounds__(256) void wprep_kernel(
    const float* __restrict__ Wq, const float* __restrict__ Wk,
    const float* __restrict__ Wv, short* __restrict__ Wf)
{
    const int g = blockIdx.x * 256 + threadIdx.x;   // 0..49151
    const int mat = g >> 14;
    const int rem = g & 16383;
    const int o   = rem >> 7;
    const int c   = rem & 127;
    const float* W = (mat == 0) ? Wq : (mat == 1) ? Wk : Wv;
    float v = W[o * CH + c];
    if (mat == 1) v *= 0.08838834764831845f;
    Wf[(size_t)mat * 16384 + (o >> 4) * 2048 + (c >> 5) * 512
       + ((c >> 3) & 3) * 128 + (o & 15) * 8 + (c & 7)] = f2bf(v);
}

// ---------------------------------------------------------------------------
// Kernel 1: QKV projection via MFMA (R12-proven structure, unchanged).
// Outputs Qf/Kf frag-major, Vp panel [n][l>>4][c][l&15].
// grid = 512 blocks x 256 thr. XCD-pinned block remap.
// ---------------------------------------------------------------------------
__global__ __launch_bounds__(256) void proj_kernel(
    const float* __restrict__ x, const short* __restrict__ Wf,
    const float* __restrict__ bq, const float* __restrict__ bk,
    const float* __restrict__ bv,
    short* __restrict__ Qf, short* __restrict__ Kf, short* __restrict__ Vp)
{
    const int i    = blockIdx.x;
    const int n    = (i >> 1) & 3;            // XCD pair {2n,2n+1}
    const int lt   = ((i >> 3) << 1) | (i & 1); // l-tile of 32 (0..127)
    const int l0   = lt << 5;
    const int tid  = threadIdx.x;
    const int wave = tid >> 6;        // 0..3
    const int lane = tid & 63;
    const int quad = lane >> 4;
    const int mc   = lane & 15;

    __shared__ short Xb[32][136];     // [l][c] bf16, +8 pad (8.7 KB)

    {
        const int sl = tid & 31;      // l
        const int cg = tid >> 5;      // c-group of 16 (0..7)
        const float* xp = x + ((size_t)n * CH + cg * 16) * LL + l0 + sl;
        short8 buf;
        #pragma unroll
        for (int i2 = 0; i2 < 16; ++i2) {
            buf[i2 & 7] = f2bf(xp[(size_t)i2 * LL]);
            if ((i2 & 7) == 7)
                *(short8*)(void*)&Xb[sl][cg * 16 + (i2 & 8)] = buf;
        }
    }
    __syncthreads();

    const int lt2 = wave >> 1;        // l-subtile of 16
    const int oh  = wave & 1;         // o-half (4 o-tiles)
    const int gt  = lt * 2 + lt2;     // global 16-l tile index

    short8 xf[4];                     // B-frags: B[k=c][col=l]
    #pragma unroll
    for (int s = 0; s < 4; ++s)
        xf[s] = *(const short8*)(const void*)&Xb[lt2 * 16 + mc][32 * s + quad * 8];

    const size_t obase = ((size_t)n * 256 + gt) * 2048;
    const float scale = 0.08838834764831845f;  // 1/sqrt(128)

    #pragma unroll
    for (int mat = 0; mat < 3; ++mat) {
        const short* Wm = Wf + (size_t)mat * 16384;
        const float* bb = (mat == 0) ? bq : (mat == 1) ? bk : bv;
        const float bscale = (mat == 1) ? scale : 1.0f;
        #pragma unroll
        for (int ot = oh * 4; ot < oh * 4 + 4; ++ot) {
            floatx4 acc = {0.f, 0.f, 0.f, 0.f};
            #pragma unroll
            for (int s = 0; s < 4; ++s)
                acc = __builtin_amdgcn_mfma_f32_16x16x32_bf16(
                    *(const short8*)(const void*)(Wm + ot * 2048 + s * 512 + lane * 8),
                    xf[s], acc, 0, 0, 0);
            const int c0 = ot * 16 + 4 * quad;
            if (mat < 2) {
                short4b pv;
                #pragma unroll
                for (int r = 0; r < 4; ++r)
                    pv[r] = f2bf(acc[r] + bb[c0 + r] * bscale);
                short* dst = ((mat == 0) ? Qf : Kf) + obase
                           + (c0 >> 5) * 512 + ((c0 >> 3) & 3) * 128
                           + mc * 8 + (c0 & 7);
                *(short4b*)(void*)dst = pv;
            } else {
                #pragma unroll
                for (int r = 0; r < 4; ++r)
                    Vp[obase + (c0 + r) * 16 + mc] = f2bf(acc[r] + bb[c0 + r]);
            }
        }
    }
}

// ---------------------------------------------------------------------------
// Kernel 2 (R18): softmax denominators -> rcpD[n][l].
// 512 blocks x 512 thr (2 blocks/CU), block = 32 l (2 K-tiles); wave w
// owns m-eighth (32 q-tiles), ping-pong Q prefetch (R14-proven inner loop).
// ---------------------------------------------------------------------------
__global__ __launch_bounds__(512, 4) void rowsum_kernel(
    const short* __restrict__ Qf, const short* __restrict__ Kf,
    float* __restrict__ Dv)
{
    const int i    = blockIdx.x;         // 512 blocks
    const int n    = (i >> 1) & 3;       // XCD pair {2n,2n+1}
    const int tp   = ((i >> 3) << 1) | (i & 1);  // 32-l group (0..127)
    const int tid  = threadIdx.x;
    const int wave = tid >> 6;           // 0..7 = m-eighth
    const int lane = tid & 63;
    const int quad = lane >> 4;
    const int mc   = lane & 15;

    __shared__ float Db[8][32];          // per-wave partial D (1 KB)

    const short* Kb = Kf + ((size_t)n * 256 + tp * 2) * 2048 + lane * 8;
    short8 kf[2][4];
    #pragma unroll
    for (int t = 0; t < 2; ++t)
        #pragma unroll
        for (int s = 0; s < 4; ++s)
            kf[t][s] = *(const short8*)(const void*)(Kb + t * 2048 + s * 512);

    const short* Qn = Qf + (size_t)n * 524288 + (size_t)wave * 32 * 2048 + lane * 8;
    float rs[2][4] = {{0.f, 0.f, 0.f, 0.f}, {0.f, 0.f, 0.f, 0.f}};

    short8 qA[4], qB[4];
    #pragma unroll
    for (int s = 0; s < 4; ++s)
        qA[s] = *(const short8*)(const void*)(Qn + s * 512);

    auto qstep = [&](const short8 (&q)[4]) {
        floatx4 a0 = {0.f, 0.f, 0.f, 0.f};
        floatx4 a1 = {0.f, 0.f, 0.f, 0.f};
        #pragma unroll
        for (int s = 0; s < 4; ++s) {
            a0 = __builtin_amdgcn_mfma_f32_16x16x32_bf16(kf[0][s], q[s], a0, 0, 0, 0);
            a1 = __builtin_amdgcn_mfma_f32_16x16x32_bf16(kf[1][s], q[s], a1, 0, 0, 0);
        }
        #pragma unroll
        for (int r = 0; r < 4; ++r) {
            rs[0][r] += __expf(a0[r]);
            rs[1][r] += __expf(a1[r]);
        }
    };

    for (int it = 0; it < 32; it += 2) {
        #pragma unroll
        for (int s = 0; s < 4; ++s)
            qB[s] = *(const short8*)(const void*)(
                Qn + (size_t)((it + 1) & 31) * 2048 + s * 512);
        qstep(qA);
        #pragma unroll
        for (int s = 0; s < 4; ++s)
            qA[s] = *(const short8*)(const void*)(
                Qn + (size_t)((it + 2) & 31) * 2048 + s * 512);
        qstep(qB);
    }

    #pragma unroll
    for (int t = 0; t < 2; ++t)
        #pragma unroll
        for (int r = 0; r < 4; ++r) {
            float v = rs[t][r];
            v += __shfl_xor(v, 1);
            v += __shfl_xor(v, 2);
            v += __shfl_xor(v, 4);
            v += __shfl_xor(v, 8);
            if (mc == 0) Db[wave][t * 16 + quad * 4 + r] = v;
        }
    __syncthreads();
    if (tid < 32) {
        float s = 0.f;
        #pragma unroll
        for (int m = 0; m < 8; ++m) s += Db[m][tid];
        Dv[(size_t)n * 4096 + tp * 32 + tid] = 1.0f / s;
    }
}

// ---------------------------------------------------------------------------
// Kernel 3 (R18): partial O over an l-half.
// grid 512 = {n, m-block 64, l-half} x 512 thr (8 waves), 2 blocks/CU.
// 8 steps of 256 l; phase A: wave w -> l-tiles 2w,2w+1 (Q per-step from
// L2-hot Qf, 16 KB/step/block); phase B: wave (ct,mh) -> full 256-l sum
// (no kh split -> no Rbuf). P dbuf 66 KB, 1 barrier/step.
// Writes partial O f32 to Po[lh][n][c][m].
// ---------------------------------------------------------------------------
__global__ __launch_bounds__(512, 4) void attn_out_kernel(
    const short* __restrict__ Qf, const short* __restrict__ Kf,
    const short* __restrict__ Vp, const float* __restrict__ Dv,
    float* __restrict__ Po)
{
    const int i    = blockIdx.x;
    const int n    = (i >> 1) & 3;               // XCD pair {2n,2n+1}
    const int j    = ((i >> 3) << 1) | (i & 1);  // 0..127
    const int lh   = j >> 6;                     // l-half
    const int mb   = j & 63;                     // m-block (0..63)
    const int m0   = mb << 6;
    const int tid  = threadIdx.x;
    const int wave = tid >> 6;          // 0..7
    const int lane = tid & 63;
    const int quad = lane >> 4;
    const int mc   = lane & 15;
    const int l32  = lane & 31;
    const int h    = lane >> 5;
    const int ct   = wave & 3;          // phase B c-tile (32 channels)
    const int mh   = wave >> 2;         // phase B m-half (32 cols)

    __shared__ short P[2][64][264];     // dbuf [m][l-local 256 +8] (66 KB)

    const short* Qn  = Qf + (size_t)n * 524288;
    const short* Kn  = Kf + (size_t)n * 524288;
    const short* Vpn = Vp + (size_t)n * 524288;
    const float* Dn  = Dv + (size_t)n * 4096;
    const int tile0  = lh * 128;        // first 16-l tile of this half

    floatx16 acc;
    #pragma unroll
    for (int r = 0; r < 16; ++r) acc[r] = 0.f;

    for (int t = 0; t < 8; ++t) {
        const int p = t & 1;

        // ---- phase A: wave w -> l-tiles {2w, 2w+1} of step t, 64 m ----
        {
            const int tb = tile0 + t * 16 + 2 * wave;
            short8 kfr[2][4];
            #pragma unroll
            for (int jj = 0; jj < 2; ++jj)
                #pragma unroll
                for (int s = 0; s < 4; ++s)
                    kfr[jj][s] = *(const short8*)(const void*)(
                        Kn + (size_t)(tb + jj) * 2048 + s * 512 + lane * 8);
            floatx4 dr[2];
            #pragma unroll
            for (int jj = 0; jj < 2; ++jj)
                dr[jj] = *(const floatx4*)(const void*)(
                    Dn + (tb + jj) * 16 + quad * 4);

            #pragma unroll
            for (int mst = 0; mst < 4; ++mst) {
                short8 qt[4];
                #pragma unroll
                for (int s = 0; s < 4; ++s)
                    qt[s] = *(const short8*)(const void*)(
                        Qn + (size_t)((m0 >> 4) + mst) * 2048 + s * 512 + lane * 8);
                floatx4 sa0 = {0.f, 0.f, 0.f, 0.f};
                floatx4 sa1 = {0.f, 0.f, 0.f, 0.f};
                #pragma unroll
                for (int s = 0; s < 4; ++s) {
                    sa0 = __builtin_amdgcn_mfma_f32_16x16x32_bf16(kfr[0][s], qt[s], sa0, 0, 0, 0);
                    sa1 = __builtin_amdgcn_mfma_f32_16x16x32_bf16(kfr[1][s], qt[s], sa1, 0, 0, 0);
                }
                short4b pv0, pv1;
                #pragma unroll
                for (int r = 0; r < 4; ++r) {
                    pv0[r] = f2bf(__expf(sa0[r]) * dr[0][r]);
                    pv1[r] = f2bf(__expf(sa1[r]) * dr[1][r]);
                }
                // C-layout (row=l=4q+r, col=m=mc) -> P[m][l-local]
                *(short4b*)(void*)&P[p][16 * mst + mc][32 * wave + quad * 4] = pv0;
                *(short4b*)(void*)&P[p][16 * mst + mc][32 * wave + 16 + quad * 4] = pv1;
            }
        }
        __syncthreads();   // only barrier: P[p] visible

        // ---- phase B: wave (ct,mh): full 256-l sum, 16 chunks ----
        #pragma unroll
        for (int kc = 0; kc < 16; ++kc) {
            const short8 vf = *(const short8*)(const void*)(
                Vpn + (size_t)(tile0 + t * 16 + kc) * 2048
                    + (32 * ct + l32) * 16 + 8 * h);
            const short8 pf = *(const short8*)(const void*)&P[p][32 * mh + l32][16 * kc + 8 * h];
            acc = __builtin_amdgcn_mfma_f32_32x32x16_bf16(vf, pf, acc, 0, 0, 0);
        }
        // no trailing barrier: next step writes P[p^1]
    }

    // ---- epilogue: write partial O (f32), 32x32 C-layout ----
    float* Pon = Po + (size_t)(lh * 4 + n) * 524288;  // [lh][n][c][m]
    #pragma unroll
    for (int r = 0; r < 16; ++r) {
        const int c = 32 * ct + (r & 3) + 8 * (r >> 2) + 4 * h;
        const int m = m0 + 32 * mh + l32;
        Pon[(size_t)c * LL + m] = acc[r];
    }
}

// ---------------------------------------------------------------------------
// Kernel 4 (R18): out = x + Po[0] + Po[1].  524288 float4s, 1 per thread.
// ---------------------------------------------------------------------------
__global__ __launch_bounds__(256) void combine_kernel(
    const float* __restrict__ x, const float* __restrict__ Po,
    float* __restrict__ out)
{
    const size_t k = (size_t)blockIdx.x * 256 + threadIdx.x;  // float4 idx
    const floatx4 a = *(const floatx4*)(const void*)(x + 4 * k);
    const floatx4 b = *(const floatx4*)(const void*)(Po + 4 * k);
    const floatx4 c = *(const floatx4*)(const void*)(Po + 2097152 + 4 * k);
    floatx4 o;
    #pragma unroll
    for (int r = 0; r < 4; ++r) o[r] = a[r] + b[r] + c[r];
    *(floatx4*)(void*)(out + 4 * k) = o;
}

// ---------------------------------------------------------------------------
extern "C" void kernel_launch(void* const* d_in, const int* in_sizes, int n_in,
                              void* d_out, int out_size, void* d_ws, size_t ws_size,
                              hipStream_t stream) {
    (void)in_sizes; (void)n_in; (void)out_size; (void)ws_size;
    const float* x  = (const float*)d_in[0];
    const float* Wq = (const float*)d_in[1];
    const float* bq = (const float*)d_in[2];
    const float* Wk = (const float*)d_in[3];
    const float* bk = (const float*)d_in[4];
    const float* Wv = (const float*)d_in[5];
    const float* bv = (const float*)d_in[6];
    float* out = (float*)d_out;

    char* ws = (char*)d_ws;
    // ws: Qf 4MB | Kf 4MB | Vp 4MB | Dv 64KB | Wf 96KB+pad | Po 16MB (~33MB)
    short* Qf = (short*)(ws);
    short* Kf = (short*)(ws + 4194304);
    short* Vp = (short*)(ws + 8388608);
    float* Dv = (float*)(ws + 12582912);
    short* Wf = (short*)(ws + 16777216);
    float* Po = (float*)(ws + 16908288);

    wprep_kernel<<<192, 256, 0, stream>>>(Wq, Wk, Wv, Wf);
    proj_kernel<<<512, 256, 0, stream>>>(x, Wf, bq, bk, bv, Qf, Kf, Vp);
    rowsum_kernel<<<512, 512, 0, stream>>>(Qf, Kf, Dv);
    attn_out_kernel<<<512, 512, 0, stream>>>(Qf, Kf, Vp, Dv, Po);
    combine_kernel<<<2048, 256, 0, stream>>>(x, Po, out);
}